// Round 12
// baseline (86.501 us; speedup 1.0000x reference)
//
#include <hip/hip_runtime.h>
#include <math.h>

#define HW     512
#define CH     16
#define PIXELS (HW * HW)          // 262144 = 2^18
#define BATCH  8
#define RED_SLICES 128            // blocks per batch in reduction

typedef float f32x4 __attribute__((ext_vector_type(4)));

// ---------------------------------------------------------------------------
// Kernel 1: per-block partial channel sums (EXACT R7). Launched TWICE this
// round as a timing probe: the 2nd launch re-reads x immediately after the
// 1st streamed it through L3, and writes bit-identical partials (output
// unchanged). Delta vs R7's 66.6 us = steady-state reduce duration + L3
// retention answer.
// ---------------------------------------------------------------------------
__global__ __launch_bounds__(256) void reduce_partial_kernel(
        const float* __restrict__ x, float* __restrict__ partial) {
    const int b = blockIdx.x >> 7;          // / RED_SLICES
    const int s = blockIdx.x & (RED_SLICES - 1);
    const float4* xp = (const float4*)(x + (size_t)b * PIXELS * CH);
    int idx = s * 8192 + threadIdx.x;
    float4 acc = make_float4(0.f, 0.f, 0.f, 0.f);
#pragma unroll 8
    for (int k = 0; k < 32; ++k) {
        float4 v = xp[idx + k * 256];
        acc.x += v.x; acc.y += v.y; acc.z += v.z; acc.w += v.w;
    }
    for (int off = 4; off < 64; off <<= 1) {
        acc.x += __shfl_xor(acc.x, off);
        acc.y += __shfl_xor(acc.y, off);
        acc.z += __shfl_xor(acc.z, off);
        acc.w += __shfl_xor(acc.w, off);
    }
    __shared__ float swave[4][CH];
    const int wave = threadIdx.x >> 6;
    const int lane = threadIdx.x & 63;
    if (lane < 4) {
        swave[wave][lane * 4 + 0] = acc.x;
        swave[wave][lane * 4 + 1] = acc.y;
        swave[wave][lane * 4 + 2] = acc.z;
        swave[wave][lane * 4 + 3] = acc.w;
    }
    __syncthreads();
    if (threadIdx.x < CH) {
        float t = swave[0][threadIdx.x] + swave[1][threadIdx.x]
                + swave[2][threadIdx.x] + swave[3][threadIdx.x];
        partial[(size_t)blockIdx.x * CH + threadIdx.x] = t;
    }
}

// ---------------------------------------------------------------------------
// Kernel 2: angle prologue + bilinear rotate — EXACT R7 kernel (proven best).
// ---------------------------------------------------------------------------
__global__ __launch_bounds__(256) void rotate_kernel(
        const float* __restrict__ x,
        const float* __restrict__ w_angle,
        const float* __restrict__ b_angle,
        const float* __restrict__ partial,
        float* __restrict__ out) {
    const int bid  = blockIdx.x;
    const int b    = bid & 7;            // batch == XCD (block-uniform)
    const int sblk = bid >> 3;           // 0..4095 within image
    const int tid  = threadIdx.x;

    __shared__ float red[16][CH];
    __shared__ float prm[4];

    {
        const int c  = tid & 15;
        const int sg = tid >> 4;         // 0..15
        float s8 = 0.f;
#pragma unroll
        for (int j = 0; j < 8; ++j)
            s8 += partial[(size_t)((b * RED_SLICES + sg + 16 * j) * CH) + c];
        red[sg][c] = s8;
        __syncthreads();
        if (tid < CH) {
            float m = 0.f;
#pragma unroll
            for (int g = 0; g < 16; ++g) m += red[g][tid];
            red[0][tid] = m * (1.0f / (float)PIXELS);   // mean_c
        }
        __syncthreads();
        if (tid == 0) {
            float dot = b_angle[0];
#pragma unroll
            for (int c2 = 0; c2 < CH; ++c2) dot += red[0][c2] * w_angle[c2];
            float tn = tanhf(dot);
            const float pi = 3.14159265358979323846f;
            float ang = fminf(fmaxf(tn * pi, -pi), pi);
            float cs = cosf(ang);
            float sn = sinf(ang);
            prm[0] = cs;
            prm[1] = sn;
            prm[2] = (511.0f - (cs * 511.0f - sn * 511.0f)) * 0.5f;  // x_off
            prm[3] = (511.0f - (sn * 511.0f + cs * 511.0f)) * 0.5f;  // y_off
        }
        __syncthreads();
    }

    const float cs = prm[0];
    const float sn = prm[1];
    const float xo = prm[2];
    const float yo = prm[3];

    const int gl = sblk * 256 + tid;     // float4 index within image
    const int q  = gl & 3;               // channel quad
    const int p  = gl >> 2;              // pixel within image
    const int oy = p >> 9;
    const int ox = p & (HW - 1);

    const float fx = (float)ox;
    const float fy = (float)oy;
    const float ix = cs * fx - sn * fy + xo;
    const float iy = sn * fx + cs * fy + yo;
    const int x0 = __float2int_rd(ix);   // floor
    const int y0 = __float2int_rd(iy);
    const float wx = ix - (float)x0;
    const float wy = iy - (float)y0;

    const float4* base = (const float4*)x + (size_t)b * PIXELS * 4 + q;

    float4 v00, v01, v10, v11;
    if (x0 >= 0 && y0 >= 0 && x0 < HW - 1 && y0 < HW - 1) {
        const float4* row0 = base + (size_t)y0 * (HW * 4);
        v00 = row0[(size_t)x0 * 4];
        v01 = row0[(size_t)(x0 + 1) * 4];
        const float4* row1 = row0 + HW * 4;
        v10 = row1[(size_t)x0 * 4];
        v11 = row1[(size_t)(x0 + 1) * 4];
    } else {
        auto read = [&](int yy, int xx) -> float4 {
            if ((unsigned)xx < (unsigned)HW && (unsigned)yy < (unsigned)HW)
                return base[((size_t)yy * HW + xx) * 4];
            return make_float4(0.f, 0.f, 0.f, 0.f);
        };
        v00 = read(y0,     x0);
        v01 = read(y0,     x0 + 1);
        v10 = read(y0 + 1, x0);
        v11 = read(y0 + 1, x0 + 1);
    }

    const float wx1 = 1.0f - wx;
    const float wy1 = 1.0f - wy;
    f32x4 r;
    r.x = (v00.x * wx1 + v01.x * wx) * wy1 + (v10.x * wx1 + v11.x * wx) * wy;
    r.y = (v00.y * wx1 + v01.y * wx) * wy1 + (v10.y * wx1 + v11.y * wx) * wy;
    r.z = (v00.z * wx1 + v01.z * wx) * wy1 + (v10.z * wx1 + v11.z * wx) * wy;
    r.w = (v00.w * wx1 + v01.w * wx) * wy1 + (v10.w * wx1 + v11.w * wx) * wy;

    __builtin_nontemporal_store(r, (f32x4*)out + (size_t)b * PIXELS * 4 + gl);
}

extern "C" void kernel_launch(void* const* d_in, const int* in_sizes, int n_in,
                              void* d_out, int out_size, void* d_ws, size_t ws_size,
                              hipStream_t stream) {
    const float* x       = (const float*)d_in[0];
    const float* w_angle = (const float*)d_in[1];
    const float* b_angle = (const float*)d_in[2];
    float* out = (float*)d_out;

    float* partial = (float*)d_ws;   // BATCH*RED_SLICES*CH = 16384 floats

    // PROBE: launch reduce twice. 2nd writes bit-identical partials (output
    // unchanged); delta vs R7 (66.6us) = steady-state reduce time, and tests
    // whether L3 serves the immediate re-read of x.
    reduce_partial_kernel<<<BATCH * RED_SLICES, 256, 0, stream>>>(x, partial);
    reduce_partial_kernel<<<BATCH * RED_SLICES, 256, 0, stream>>>(x, partial);
    rotate_kernel<<<BATCH * PIXELS * 4 / 256, 256, 0, stream>>>(
        x, w_angle, b_angle, partial, out);
}

// Round 13
// 69.822 us; speedup vs baseline: 1.2389x; 1.2389x over previous
//
#include <hip/hip_runtime.h>
#include <math.h>

#define HW     512
#define CH     16
#define PIXELS (HW * HW)          // 262144 = 2^18
#define BATCH  8
#define RED_SLICES 64             // reduce blocks per batch (512 total)

typedef float f32x4 __attribute__((ext_vector_type(4)));

// ---------------------------------------------------------------------------
// Kernel 1: per-block partial channel sums. 512 blocks x 512 threads =
// 2 blocks/CU x 8 waves = 16 waves/CU (same occupancy as R7's reduce, which
// R12's probe showed is at the 6.4 TB/s HBM floor). 32 float4/thread, fixed
// order -> deterministic. Layout: partial[(b*64+s)*16 + c].
// ---------------------------------------------------------------------------
__global__ __launch_bounds__(512) void reduce_partial_kernel(
        const float* __restrict__ x, float* __restrict__ partial) {
    const int b = blockIdx.x >> 6;          // / RED_SLICES
    const int s = blockIdx.x & (RED_SLICES - 1);
    const int tid = threadIdx.x;
    const float4* xp = (const float4*)(x + (size_t)b * PIXELS * CH);
    // float4s per batch = 1048576; per block(slice) = 16384; per thread = 32
    int idx = s * 16384 + tid;
    float4 acc = make_float4(0.f, 0.f, 0.f, 0.f);
#pragma unroll 8
    for (int k = 0; k < 32; ++k) {
        float4 v = xp[idx + k * 512];
        acc.x += v.x; acc.y += v.y; acc.z += v.z; acc.w += v.w;
    }
    // reduce across the 16 lanes sharing (lane & 3): channel quad is lane&3
    for (int off = 4; off < 64; off <<= 1) {
        acc.x += __shfl_xor(acc.x, off);
        acc.y += __shfl_xor(acc.y, off);
        acc.z += __shfl_xor(acc.z, off);
        acc.w += __shfl_xor(acc.w, off);
    }
    __shared__ float swave[8][CH];
    const int wave = tid >> 6;
    const int lane = tid & 63;
    if (lane < 4) {
        swave[wave][lane * 4 + 0] = acc.x;
        swave[wave][lane * 4 + 1] = acc.y;
        swave[wave][lane * 4 + 2] = acc.z;
        swave[wave][lane * 4 + 3] = acc.w;
    }
    __syncthreads();
    if (tid < CH) {
        float t = 0.f;
#pragma unroll
        for (int w = 0; w < 8; ++w) t += swave[w][tid];
        partial[(size_t)blockIdx.x * CH + tid] = t;
    }
}

// ---------------------------------------------------------------------------
// Kernel 2: angle prologue + bilinear rotate. Gather identical to R7 (proven
// best: 32768 x 256, 1 float4/thread). Prologue halved: 4 loads/thread,
// 4 KB/block of XCD-local L2 traffic (was 8). b = bid & 7 -> XCD owns image.
// ---------------------------------------------------------------------------
__global__ __launch_bounds__(256) void rotate_kernel(
        const float* __restrict__ x,
        const float* __restrict__ w_angle,
        const float* __restrict__ b_angle,
        const float* __restrict__ partial,
        float* __restrict__ out) {
    const int bid  = blockIdx.x;
    const int b    = bid & 7;            // batch == XCD (block-uniform)
    const int sblk = bid >> 3;           // 0..4095 within image
    const int tid  = threadIdx.x;

    __shared__ float red[16][CH];
    __shared__ float prm[4];

    // ---- prologue: this batch's rotation params from partials ----
    {
        const int c  = tid & 15;
        const int sg = tid >> 4;         // 0..15
        float s4 = 0.f;
#pragma unroll
        for (int j = 0; j < 4; ++j)
            s4 += partial[(size_t)((b * RED_SLICES + sg + 16 * j) * CH) + c];
        red[sg][c] = s4;
        __syncthreads();
        if (tid < CH) {
            float m = 0.f;
#pragma unroll
            for (int g = 0; g < 16; ++g) m += red[g][tid];
            red[0][tid] = m * (1.0f / (float)PIXELS);   // mean_c
        }
        __syncthreads();
        if (tid == 0) {
            float dot = b_angle[0];
#pragma unroll
            for (int c2 = 0; c2 < CH; ++c2) dot += red[0][c2] * w_angle[c2];
            float tn = tanhf(dot);
            const float pi = 3.14159265358979323846f;
            float ang = fminf(fmaxf(tn * pi, -pi), pi);
            float cs = cosf(ang);
            float sn = sinf(ang);
            prm[0] = cs;
            prm[1] = sn;
            prm[2] = (511.0f - (cs * 511.0f - sn * 511.0f)) * 0.5f;  // x_off
            prm[3] = (511.0f - (sn * 511.0f + cs * 511.0f)) * 0.5f;  // y_off
        }
        __syncthreads();
    }

    const float cs = prm[0];
    const float sn = prm[1];
    const float xo = prm[2];
    const float yo = prm[3];

    // ---- gather: 1 float4 (4 channels) per thread ----
    const int gl = sblk * 256 + tid;     // float4 index within image
    const int q  = gl & 3;               // channel quad
    const int p  = gl >> 2;              // pixel within image
    const int oy = p >> 9;
    const int ox = p & (HW - 1);

    const float fx = (float)ox;
    const float fy = (float)oy;
    const float ix = cs * fx - sn * fy + xo;
    const float iy = sn * fx + cs * fy + yo;
    const int x0 = __float2int_rd(ix);   // floor
    const int y0 = __float2int_rd(iy);
    const float wx = ix - (float)x0;
    const float wy = iy - (float)y0;

    const float4* base = (const float4*)x + (size_t)b * PIXELS * 4 + q;

    float4 v00, v01, v10, v11;
    if (x0 >= 0 && y0 >= 0 && x0 < HW - 1 && y0 < HW - 1) {
        // interior: all four taps valid (overwhelmingly common)
        const float4* row0 = base + (size_t)y0 * (HW * 4);
        v00 = row0[(size_t)x0 * 4];
        v01 = row0[(size_t)(x0 + 1) * 4];
        const float4* row1 = row0 + HW * 4;
        v10 = row1[(size_t)x0 * 4];
        v11 = row1[(size_t)(x0 + 1) * 4];
    } else {
        auto read = [&](int yy, int xx) -> float4 {
            if ((unsigned)xx < (unsigned)HW && (unsigned)yy < (unsigned)HW)
                return base[((size_t)yy * HW + xx) * 4];
            return make_float4(0.f, 0.f, 0.f, 0.f);
        };
        v00 = read(y0,     x0);
        v01 = read(y0,     x0 + 1);
        v10 = read(y0 + 1, x0);
        v11 = read(y0 + 1, x0 + 1);
    }

    const float wx1 = 1.0f - wx;
    const float wy1 = 1.0f - wy;
    f32x4 r;
    r.x = (v00.x * wx1 + v01.x * wx) * wy1 + (v10.x * wx1 + v11.x * wx) * wy;
    r.y = (v00.y * wx1 + v01.y * wx) * wy1 + (v10.y * wx1 + v11.y * wx) * wy;
    r.z = (v00.z * wx1 + v01.z * wx) * wy1 + (v10.z * wx1 + v11.z * wx) * wy;
    r.w = (v00.w * wx1 + v01.w * wx) * wy1 + (v10.w * wx1 + v11.w * wx) * wy;

    __builtin_nontemporal_store(r, (f32x4*)out + (size_t)b * PIXELS * 4 + gl);
}

extern "C" void kernel_launch(void* const* d_in, const int* in_sizes, int n_in,
                              void* d_out, int out_size, void* d_ws, size_t ws_size,
                              hipStream_t stream) {
    const float* x       = (const float*)d_in[0];
    const float* w_angle = (const float*)d_in[1];
    const float* b_angle = (const float*)d_in[2];
    float* out = (float*)d_out;

    float* partial = (float*)d_ws;   // BATCH*RED_SLICES*CH = 8192 floats

    reduce_partial_kernel<<<BATCH * RED_SLICES, 512, 0, stream>>>(x, partial);
    rotate_kernel<<<BATCH * PIXELS * 4 / 256, 256, 0, stream>>>(
        x, w_angle, b_angle, partial, out);
}

// Round 14
// 67.591 us; speedup vs baseline: 1.2798x; 1.0330x over previous
//
#include <hip/hip_runtime.h>
#include <math.h>

#define HW     512
#define CH     16
#define PIXELS (HW * HW)          // 262144 = 2^18
#define BATCH  8
#define RED_SLICES 128            // blocks per batch in reduction

typedef float f32x4 __attribute__((ext_vector_type(4)));

// ---------------------------------------------------------------------------
// Kernel 1: per-block partial channel sums (EXACT R7 — proven best).
// 1024 blocks x 256. Layout: partial[(b*128+s)*16 + c].
// ---------------------------------------------------------------------------
__global__ __launch_bounds__(256) void reduce_partial_kernel(
        const float* __restrict__ x, float* __restrict__ partial) {
    const int b = blockIdx.x >> 7;          // / RED_SLICES
    const int s = blockIdx.x & (RED_SLICES - 1);
    const float4* xp = (const float4*)(x + (size_t)b * PIXELS * CH);
    int idx = s * 8192 + threadIdx.x;
    float4 acc = make_float4(0.f, 0.f, 0.f, 0.f);
#pragma unroll 8
    for (int k = 0; k < 32; ++k) {
        float4 v = xp[idx + k * 256];
        acc.x += v.x; acc.y += v.y; acc.z += v.z; acc.w += v.w;
    }
    for (int off = 4; off < 64; off <<= 1) {
        acc.x += __shfl_xor(acc.x, off);
        acc.y += __shfl_xor(acc.y, off);
        acc.z += __shfl_xor(acc.z, off);
        acc.w += __shfl_xor(acc.w, off);
    }
    __shared__ float swave[4][CH];
    const int wave = threadIdx.x >> 6;
    const int lane = threadIdx.x & 63;
    if (lane < 4) {
        swave[wave][lane * 4 + 0] = acc.x;
        swave[wave][lane * 4 + 1] = acc.y;
        swave[wave][lane * 4 + 2] = acc.z;
        swave[wave][lane * 4 + 3] = acc.w;
    }
    __syncthreads();
    if (threadIdx.x < CH) {
        float t = swave[0][threadIdx.x] + swave[1][threadIdx.x]
                + swave[2][threadIdx.x] + swave[3][threadIdx.x];
        partial[(size_t)blockIdx.x * CH + threadIdx.x] = t;
    }
}

// ---------------------------------------------------------------------------
// Kernel 2: angle prologue + bilinear rotate — R7 with ONE change:
// normal cached stores instead of nontemporal (harness fills prove cached
// stores sustain 7.1 TB/s; R12 proved there is no L3-retention of x to
// protect, voiding NT's original justification).
// ---------------------------------------------------------------------------
__global__ __launch_bounds__(256) void rotate_kernel(
        const float* __restrict__ x,
        const float* __restrict__ w_angle,
        const float* __restrict__ b_angle,
        const float* __restrict__ partial,
        float* __restrict__ out) {
    const int bid  = blockIdx.x;
    const int b    = bid & 7;            // batch == XCD (block-uniform)
    const int sblk = bid >> 3;           // 0..4095 within image
    const int tid  = threadIdx.x;

    __shared__ float red[16][CH];
    __shared__ float prm[4];

    // ---- prologue: this batch's rotation params from partials ----
    {
        const int c  = tid & 15;
        const int sg = tid >> 4;         // 0..15
        float s8 = 0.f;
#pragma unroll
        for (int j = 0; j < 8; ++j)
            s8 += partial[(size_t)((b * RED_SLICES + sg + 16 * j) * CH) + c];
        red[sg][c] = s8;
        __syncthreads();
        if (tid < CH) {
            float m = 0.f;
#pragma unroll
            for (int g = 0; g < 16; ++g) m += red[g][tid];
            red[0][tid] = m * (1.0f / (float)PIXELS);   // mean_c
        }
        __syncthreads();
        if (tid == 0) {
            float dot = b_angle[0];
#pragma unroll
            for (int c2 = 0; c2 < CH; ++c2) dot += red[0][c2] * w_angle[c2];
            float tn = tanhf(dot);
            const float pi = 3.14159265358979323846f;
            float ang = fminf(fmaxf(tn * pi, -pi), pi);
            float cs = cosf(ang);
            float sn = sinf(ang);
            prm[0] = cs;
            prm[1] = sn;
            prm[2] = (511.0f - (cs * 511.0f - sn * 511.0f)) * 0.5f;  // x_off
            prm[3] = (511.0f - (sn * 511.0f + cs * 511.0f)) * 0.5f;  // y_off
        }
        __syncthreads();
    }

    const float cs = prm[0];
    const float sn = prm[1];
    const float xo = prm[2];
    const float yo = prm[3];

    // ---- gather: 1 float4 (4 channels) per thread ----
    const int gl = sblk * 256 + tid;     // float4 index within image
    const int q  = gl & 3;               // channel quad
    const int p  = gl >> 2;              // pixel within image
    const int oy = p >> 9;
    const int ox = p & (HW - 1);

    const float fx = (float)ox;
    const float fy = (float)oy;
    const float ix = cs * fx - sn * fy + xo;
    const float iy = sn * fx + cs * fy + yo;
    const int x0 = __float2int_rd(ix);   // floor
    const int y0 = __float2int_rd(iy);
    const float wx = ix - (float)x0;
    const float wy = iy - (float)y0;

    const float4* base = (const float4*)x + (size_t)b * PIXELS * 4 + q;

    float4 v00, v01, v10, v11;
    if (x0 >= 0 && y0 >= 0 && x0 < HW - 1 && y0 < HW - 1) {
        // interior: all four taps valid (overwhelmingly common)
        const float4* row0 = base + (size_t)y0 * (HW * 4);
        v00 = row0[(size_t)x0 * 4];
        v01 = row0[(size_t)(x0 + 1) * 4];
        const float4* row1 = row0 + HW * 4;
        v10 = row1[(size_t)x0 * 4];
        v11 = row1[(size_t)(x0 + 1) * 4];
    } else {
        auto read = [&](int yy, int xx) -> float4 {
            if ((unsigned)xx < (unsigned)HW && (unsigned)yy < (unsigned)HW)
                return base[((size_t)yy * HW + xx) * 4];
            return make_float4(0.f, 0.f, 0.f, 0.f);
        };
        v00 = read(y0,     x0);
        v01 = read(y0,     x0 + 1);
        v10 = read(y0 + 1, x0);
        v11 = read(y0 + 1, x0 + 1);
    }

    const float wx1 = 1.0f - wx;
    const float wy1 = 1.0f - wy;
    float4 r;
    r.x = (v00.x * wx1 + v01.x * wx) * wy1 + (v10.x * wx1 + v11.x * wx) * wy;
    r.y = (v00.y * wx1 + v01.y * wx) * wy1 + (v10.y * wx1 + v11.y * wx) * wy;
    r.z = (v00.z * wx1 + v01.z * wx) * wy1 + (v10.z * wx1 + v11.z * wx) * wy;
    r.w = (v00.w * wx1 + v01.w * wx) * wy1 + (v10.w * wx1 + v11.w * wx) * wy;

    ((float4*)out)[(size_t)b * PIXELS * 4 + gl] = r;   // normal cached store
}

extern "C" void kernel_launch(void* const* d_in, const int* in_sizes, int n_in,
                              void* d_out, int out_size, void* d_ws, size_t ws_size,
                              hipStream_t stream) {
    const float* x       = (const float*)d_in[0];
    const float* w_angle = (const float*)d_in[1];
    const float* b_angle = (const float*)d_in[2];
    float* out = (float*)d_out;

    float* partial = (float*)d_ws;   // BATCH*RED_SLICES*CH = 16384 floats

    reduce_partial_kernel<<<BATCH * RED_SLICES, 256, 0, stream>>>(x, partial);
    rotate_kernel<<<BATCH * PIXELS * 4 / 256, 256, 0, stream>>>(
        x, w_angle, b_angle, partial, out);
}